// Round 1
// baseline (112.839 us; speedup 1.0000x reference)
//
#include <hip/hip_runtime.h>

#define B_N 4096
#define C_N 128
#define E_N 10

// ---------------------------------------------------------------------------
// Kernel 1: bucket nodes by element (y is one-hot over E=10).
// ws layout: cnt[10] ints at offset 0 (zeroed via hipMemsetAsync before),
//            list[10*4096] ints at byte offset 64.
// ---------------------------------------------------------------------------
__global__ __launch_bounds__(256) void build_lists_kernel(
    const float* __restrict__ y, int* __restrict__ cnt, int* __restrict__ list)
{
    int b = blockIdx.x * 256 + threadIdx.x;
    if (b >= B_N) return;
    const float* yb = y + (size_t)b * E_N;
    int e = 0;
#pragma unroll
    for (int j = 1; j < E_N; ++j) e = (yb[j] > 0.5f) ? j : e;
    int pos = atomicAdd(&cnt[e], 1);
    list[e * B_N + pos] = b;
}

// ---------------------------------------------------------------------------
// Kernel 2: main contraction. One block = (channel c, element e, chunk of 256
// nodes with that element). Block builds the per-(e,c) contracted tensors
// T3/T2/T1 (s and v) into LDS (13.1 KB), then each thread computes one node's
// 4 outputs with ~3276 FMAs against LDS-broadcast table values.
// ---------------------------------------------------------------------------
__global__ __launch_bounds__(256) void sc_main_kernel(
    const float* __restrict__ x,
    const int* __restrict__ cnt, const int* __restrict__ list,
    const float* __restrict__ U1s, const float* __restrict__ U2s, const float* __restrict__ U3s,
    const float* __restrict__ W1s, const float* __restrict__ W2s, const float* __restrict__ W3s,
    const float* __restrict__ U1v, const float* __restrict__ U2v, const float* __restrict__ U3v,
    const float* __restrict__ W1v, const float* __restrict__ W2v, const float* __restrict__ W3v,
    float* __restrict__ out)
{
    const int c     = blockIdx.x;   // 0..127
    const int e     = blockIdx.y;   // 0..9
    const int chunk = blockIdx.z;   // 0..15

    const int n    = cnt[e];
    const int base = chunk * 256;
    if (base >= n) return;          // uniform early exit (before any barrier)

    __shared__ float T3s[729], T2s[81], T1s[9];
    __shared__ float T3v[2187], T2v[243], T1v[27];

    const int tid = threadIdx.x;

    // ---- build tables: T = sum_k U[..,k] * W[e,k,c] (addresses block-uniform
    //      except the i index -> W reads become scalar loads) ----
    for (int i = tid; i < 729; i += 256) {
        const float* u = U3s + (size_t)i * 23;
        float t = 0.f;
#pragma unroll
        for (int k = 0; k < 23; ++k) t = fmaf(u[k], W3s[(e * 23 + k) * C_N + c], t);
        T3s[i] = t;
    }
    for (int i = tid; i < 2187; i += 256) {
        const float* u = U3v + (size_t)i * 15;
        float t = 0.f;
#pragma unroll
        for (int k = 0; k < 15; ++k) t = fmaf(u[k], W3v[(e * 15 + k) * C_N + c], t);
        T3v[i] = t;
    }
    for (int i = tid; i < 81; i += 256) {
        float t = 0.f;
#pragma unroll
        for (int k = 0; k < 3; ++k) t = fmaf(U2s[i * 3 + k], W2s[(e * 3 + k) * C_N + c], t);
        T2s[i] = t;
    }
    for (int i = tid; i < 243; i += 256) {
        float t = 0.f;
#pragma unroll
        for (int k = 0; k < 4; ++k) t = fmaf(U2v[i * 4 + k], W2v[(e * 4 + k) * C_N + c], t);
        T2v[i] = t;
    }
    if (tid < 9)  T1s[tid] = U1s[tid] * W1s[e * C_N + c];
    if (tid < 27) T1v[tid] = U1v[tid] * W1v[e * C_N + c];

    __syncthreads();

    const int idx = base + tid;
    if (idx >= n) return;
    const int b = list[e * B_N + idx];

    const float* xp = x + ((size_t)b * C_N + c) * 9;
    float xr[9];
#pragma unroll
    for (int i = 0; i < 9; ++i) xr[i] = xp[i];

    // ---- scalar output ----
    {
        float os = 0.f;
#pragma unroll
        for (int i1 = 0; i1 < 9; ++i1) {
            float o1 = 0.f;
#pragma unroll
            for (int i2 = 0; i2 < 9; ++i2) {
                const float* p = &T3s[(i1 * 9 + i2) * 9];
                float t = T2s[i1 * 9 + i2];
#pragma unroll
                for (int i3 = 0; i3 < 9; ++i3) t = fmaf(p[i3], xr[i3], t);
                o1 = fmaf(t, xr[i2], o1);
            }
            os = fmaf(T1s[i1] + o1, xr[i1], os);
        }
        out[(size_t)b * 512 + c] = os;
    }

    // ---- vector output (3 components) ----
#pragma unroll
    for (int a = 0; a < 3; ++a) {
        const float* T3 = &T3v[a * 729];
        const float* T2 = &T2v[a * 81];
        const float* T1 = &T1v[a * 9];
        float ov = 0.f;
#pragma unroll
        for (int i1 = 0; i1 < 9; ++i1) {
            float o1 = 0.f;
#pragma unroll
            for (int i2 = 0; i2 < 9; ++i2) {
                const float* p = &T3[(i1 * 9 + i2) * 9];
                float t = T2[i1 * 9 + i2];
#pragma unroll
                for (int i3 = 0; i3 < 9; ++i3) t = fmaf(p[i3], xr[i3], t);
                o1 = fmaf(t, xr[i2], o1);
            }
            ov = fmaf(T1[i1] + o1, xr[i1], ov);
        }
        out[(size_t)b * 512 + 128 + c * 3 + a] = ov;
    }
}

// ---------------------------------------------------------------------------
extern "C" void kernel_launch(void* const* d_in, const int* in_sizes, int n_in,
                              void* d_out, int out_size, void* d_ws, size_t ws_size,
                              hipStream_t stream) {
    const float* x   = (const float*)d_in[0];
    const float* y   = (const float*)d_in[1];
    const float* U1s = (const float*)d_in[2];
    const float* U2s = (const float*)d_in[3];
    const float* U3s = (const float*)d_in[4];
    const float* W1s = (const float*)d_in[5];
    const float* W2s = (const float*)d_in[6];
    const float* W3s = (const float*)d_in[7];
    const float* U1v = (const float*)d_in[8];
    const float* U2v = (const float*)d_in[9];
    const float* U3v = (const float*)d_in[10];
    const float* W1v = (const float*)d_in[11];
    const float* W2v = (const float*)d_in[12];
    const float* W3v = (const float*)d_in[13];
    float* out = (float*)d_out;

    int* cnt  = (int*)d_ws;
    int* list = (int*)((char*)d_ws + 64);

    hipMemsetAsync(d_ws, 0, 64, stream);
    build_lists_kernel<<<dim3(16), dim3(256), 0, stream>>>(y, cnt, list);
    sc_main_kernel<<<dim3(128, 10, 16), dim3(256), 0, stream>>>(
        x, cnt, list,
        U1s, U2s, U3s, W1s, W2s, W3s,
        U1v, U2v, U3v, W1v, W2v, W3v,
        out);
}